// Round 7
// baseline (270.930 us; speedup 1.0000x reference)
//
#include <hip/hip_runtime.h>
#include <math.h>

// Problem constants (fixed by the reference)
#define BATCH 65536
#define DIM 128
#define NBAS 6
#define OUTW 896              // DIM*NBAS + DIM
#define CHROWS 8              // rows per basis block
#define BAS_F 768             // basis row stride (floats) = DIM*NBAS

typedef float f4v __attribute__((ext_vector_type(4)));
typedef float f32x4 __attribute__((ext_vector_type(4)));
typedef _Float16 f16x8 __attribute__((ext_vector_type(8)));

// ---------------------------------------------------------------------------
// Kernel 1: ST = sigmoid(W)^T in fp16 (ST[j][i] = sigmoid(W[i][j])).
// B^T row-major so MFMA B-fragments are k-contiguous 16B loads.
// ---------------------------------------------------------------------------
__global__ __launch_bounds__(256) void sigmoid_kT(const float* __restrict__ W,
                                                  _Float16* __restrict__ ST) {
    int t = blockIdx.x * 256 + threadIdx.x;
    int i = t >> 7;            // W row
    int j = t & 127;           // W col
    float w = W[t];
    float s = 1.0f / (1.0f + expf(-w));
    ST[j * 128 + i] = (_Float16)s;
}

// ---------------------------------------------------------------------------
// Kernel 2: interaction GEMM via MFMA — NO LDS, NO barriers.
// out[r][768+j] = sum_i x[r][i]^2 * S[i][j].
// Block = 256 thr = 4 waves; block covers 32 rows. Wave w: rows (w&1)*16..+15,
// cols (w>>1)*64..+63 (4 col-tiles x 4 K-steps = 16 mfma_f32_16x16x32_f16).
// A-fragments are built in-register: lane (lr,lg) reads X[row][kk*32+lg*8..+7]
// (two coalesced float4s), squares, converts. Tiling/layout identical to the
// round-6 kernel that passed the harness.
// ---------------------------------------------------------------------------
__global__ __launch_bounds__(256) void gemm_k(const float* __restrict__ X,
                                              const _Float16* __restrict__ ST,
                                              float* __restrict__ out) {
    const int tid = threadIdx.x;
    const int w = tid >> 6, l = tid & 63;
    const int lr = l & 15, lg = l >> 4;
    const int rt = w & 1;
    const int ch = w >> 1;
    const int rowA = blockIdx.x * 32 + rt * 16 + lr;   // A-fragment row

    // A-fragments from global (L2/L3-resident X), squared+converted in-reg.
    const float4* xr = (const float4*)(X + (size_t)rowA * DIM);
    f16x8 af[4];
#pragma unroll
    for (int kk = 0; kk < 4; ++kk) {
        float4 a = xr[kk * 8 + lg * 2 + 0];
        float4 b = xr[kk * 8 + lg * 2 + 1];
        f16x8 v = {(_Float16)(a.x * a.x), (_Float16)(a.y * a.y),
                   (_Float16)(a.z * a.z), (_Float16)(a.w * a.w),
                   (_Float16)(b.x * b.x), (_Float16)(b.y * b.y),
                   (_Float16)(b.z * b.z), (_Float16)(b.w * b.w)};
        af[kk] = v;
    }

    f32x4 acc[4];
#pragma unroll
    for (int ct = 0; ct < 4; ++ct) acc[ct] = (f32x4){0.f, 0.f, 0.f, 0.f};

    const char* stb = (const char*)ST;
#pragma unroll
    for (int ct = 0; ct < 4; ++ct) {
        const char* bp = stb + (ch * 64 + ct * 16 + lr) * 256 + lg * 16;
#pragma unroll
        for (int kk = 0; kk < 4; ++kk) {
            f16x8 bf = *(const f16x8*)(bp + kk * 64);
            acc[ct] = __builtin_amdgcn_mfma_f32_16x16x32_f16(af[kk], bf, acc[ct], 0, 0, 0);
        }
    }

    // C layout (m89-verified): col = ch*64+ct*16+lr, row = rt*16 + lg*4 + q.
    const int rowC0 = blockIdx.x * 32 + rt * 16 + lg * 4;
#pragma unroll
    for (int ct = 0; ct < 4; ++ct) {
        int colb = ch * 64 + ct * 16 + lr;
#pragma unroll
        for (int q = 0; q < 4; ++q) {
            __builtin_nontemporal_store(
                acc[ct][q],
                out + (size_t)(rowC0 + q) * OUTW + DIM * NBAS + colb);
        }
    }
}

// ---------------------------------------------------------------------------
// Closed-form uniform cubic B-spline weights (identical math to the
// Cox-de Boor ladder for knots = linspace(-1,1,10)).
// ---------------------------------------------------------------------------
__device__ __forceinline__ void bw(float x, int& s,
                                   float& w0, float& w1, float& w2, float& w3) {
    const float i6 = 0.16666666666666666f;
    float xc = fminf(fmaxf(x, -1.0f), 1.0f - 1e-6f);
    float p  = (xc + 1.0f) * 4.5f;
    float sf = floorf(p);
    float u  = p - sf;
    s = (int)sf;                       // 0..8
    float u2 = u * u;
    float v  = 1.0f - u;
    w0 = u * u2 * i6;                                       // t = s
    w1 = (((-3.0f * u + 3.0f) * u + 3.0f) * u + 1.0f) * i6; // t = s-1
    w2 = ((3.0f * u - 6.0f) * u2 + 4.0f) * i6;              // t = s-2
    w3 = v * v * v * i6;                                    // t = s-3
}

// ---------------------------------------------------------------------------
// Kernel 3: basis via LDS scatter (round-5-validated internals), restructured:
// one 8-row chunk per block, 8192 blocks, 24KB LDS -> 6 blocks/CU
// (24 waves/CU), and only TWO barriers per block (vs 8 in the fused version).
// x comes straight from global (L3-resident after gemm_k touched it).
// ---------------------------------------------------------------------------
__global__ __launch_bounds__(256, 6) void basis_k(const float* __restrict__ X,
                                                  float* __restrict__ out) {
    __shared__ __align__(16) float bas[CHROWS * BAS_F];   // 24 KB
    f4v* bas4 = (f4v*)bas;

    const int tid = threadIdx.x;
    const int row0 = blockIdx.x * CHROWS;

    // zero the chunk
    f4v z4 = {0.0f, 0.0f, 0.0f, 0.0f};
#pragma unroll
    for (int k = 0; k < 6; ++k) bas4[k * 256 + tid] = z4;   // 1536 f4
    __syncthreads();

    // scatter: 32 threads/row, 4 features per thread; each (row,feature)
    // owned by exactly one thread -> no write races.
    const int sr = tid >> 5;             // chunk-local row 0..7
    const int f0 = tid & 31;
    const float* xrow = X + (size_t)(row0 + sr) * DIM;
    float* basr = bas + sr * BAS_F;
#pragma unroll
    for (int m = 0; m < 4; ++m) {
        int f = f0 + 32 * m;
        float x = xrow[f];               // coalesced 128B per row-group
        int s;
        float w0, w1, w2, w3;
        bw(x, s, w0, w1, w2, w3);
        float* bp = basr + f * NBAS + s;
        // slot t = s-d must lie in [0,5]; out-of-range weights dropped
        // (matches the reference's truncated knot vector).
        if (s <= 5)           bp[0]  = w0;
        if (s >= 1 && s <= 6) bp[-1] = w1;
        if (s >= 2 && s <= 7) bp[-2] = w2;
        if (s >= 3)           bp[-3] = w3;   // s<=8 always
    }
    __syncthreads();

    // copy-out: contiguous b128 reads -> coalesced NT float4 stores.
    float* ob = out + (size_t)row0 * OUTW;
#pragma unroll
    for (int k = 0; k < 6; ++k) {
        int idx = k * 256 + tid;         // f4 idx in chunk, 0..1535
        int r = idx / 192;               // 192 f4 per row
        int j = idx - r * 192;
        f4v v = bas4[idx];
        __builtin_nontemporal_store(v, (f4v*)(ob + (size_t)r * OUTW + 4 * j));
    }
}

// ---------------------------------------------------------------------------
extern "C" void kernel_launch(void* const* d_in, const int* in_sizes, int n_in,
                              void* d_out, int out_size, void* d_ws, size_t ws_size,
                              hipStream_t stream) {
    const float* X = (const float*)d_in[0];
    const float* W = (const float*)d_in[1];
    float* out = (float*)d_out;
    _Float16* ST = (_Float16*)d_ws;   // 32 KB scratch: sigmoid(W)^T in fp16

    sigmoid_kT<<<(DIM * DIM) / 256, 256, 0, stream>>>(W, ST);
    gemm_k<<<BATCH / 32, 256, 0, stream>>>(X, ST, out);
    basis_k<<<BATCH / CHROWS, 256, 0, stream>>>(X, out);
}